// Round 1
// baseline (4870.573 us; speedup 1.0000x reference)
//
#include <hip/hip_runtime.h>
#include <hip/hip_fp16.h>

// =====================================================================
// GCN pipeline on MI355X, round 0: correctness-first fp32/fp16 version.
//
// Stages:
//  0. convert W_lin1/2, W_conv1/2 to fp16; fold center part of W_lin (sum over j).
//  1. per-(b,dim) min/max  -> quantize scale
//  2. morton/hilbert keys (x4) as (key<<12)|idx 64-bit composites
//  3. LDS bitonic sort per (b,method) -> window neighbor indices (stable argsort replica)
//  4. transpose feats (B,C,N)->(B,N,C) for coalesced gathers
//  5. fused per-window kernel (x2 layers): gather -> fp16 x_diff -> 4-head attention
//     (heads 0-3 are provably identity) -> fused = Wfold*center + Wdiff*out + b
//     -> conv -> max_k + atomic stats (norm/lrelu commute with max)
//  6. stats -> normalize+lrelu (writes both (B,C,N) and (B,N,C) layouts as needed)
//  7. final 1024->256 conv + stats -> normalize+lrelu -> d_out
// =====================================================================

// ---------------- workspace layout (bytes) ----------------
constexpr size_t OFF_S1a    = 0;
constexpr size_t OFF_S2a    = OFF_S1a + 64ull*2*256*4;
constexpr size_t OFF_S1b    = OFF_S2a + 64ull*2*256*4;
constexpr size_t OFF_S2b    = OFF_S1b + 64ull*2*512*4;
constexpr size_t OFF_S1f    = OFF_S2b + 64ull*2*512*4;
constexpr size_t OFF_S2f    = OFF_S1f + 64ull*2*256*4;
constexpr size_t STATS_BYTES= OFF_S2f + 64ull*2*256*4;      // 1 MiB, memset to 0 each call
constexpr size_t OFF_MU1    = STATS_BYTES;
constexpr size_t OFF_RS1    = OFF_MU1 + 2048;
constexpr size_t OFF_MU2    = OFF_RS1 + 2048;
constexpr size_t OFF_RS2    = OFF_MU2 + 4096;
constexpr size_t OFF_MU3    = OFF_RS2 + 4096;
constexpr size_t OFF_RS3    = OFF_MU3 + 2048;
constexpr size_t OFF_MM     = OFF_RS3 + 2048;               // 12 floats (cmin, scale)
constexpr size_t OFF_KEYS   = OFF_MM + 256;
constexpr size_t OFF_INDS   = OFF_KEYS + 8ull*4096*8;
constexpr size_t OFF_WL1H   = OFF_INDS + 8ull*4096*10*4;
constexpr size_t OFF_WL2H   = OFF_WL1H + 512ull*2048*2;
constexpr size_t OFF_WF1    = OFF_WL2H + 512ull*2048*2;
constexpr size_t OFF_WF2    = OFF_WF1  + 512ull*256*2;
constexpr size_t OFF_WC1H   = OFF_WF2  + 512ull*256*2;
constexpr size_t OFF_WC2H   = OFF_WC1H + 256ull*512*2;
constexpr size_t OFF_FEATST = OFF_WC2H + 512ull*512*2;      // (B,N,256) fp32, 8 MB
constexpr size_t OFF_F1T    = OFF_FEATST + 2ull*4096*256*4; // (B,N,256)
constexpr size_t OFF_F2N    = OFF_F1T   + 2ull*4096*256*4;  // (B,512,N)
constexpr size_t OFF_HMAX1  = OFF_F2N   + 2ull*4096*512*4;  // (B,256,N)
constexpr size_t OFF_HMAX2  = OFF_HMAX1 + 2ull*4096*256*4;  // (B,512,N)
constexpr size_t WS_NEED    = OFF_HMAX2 + 2ull*4096*512*4;  // ~63.8 MB
// Safe aliases (lifetime-disjoint):
constexpr size_t OFF_F1N    = OFF_FEATST;   // featsT dead after layer-1 window kernel
constexpr size_t OFF_H3     = OFF_HMAX1;    // hmax1 dead after normalize1

// ---------------- small device helpers ----------------
__device__ __forceinline__ int gcn_quant1(float c, float cmin, float scale) {
  // bit-exact replica of floor((c - cmin) * scale) in strict fp32 (no fma contraction)
  float q = floorf(__fmul_rn(__fsub_rn(c, cmin), scale));
  q = fminf(fmaxf(q, 0.0f), 1023.0f);
  return (int)q;
}

__device__ __forceinline__ unsigned int gcn_morton3(int x, int y, int z) {
  unsigned int key = 0u;
#pragma unroll
  for (int b = 0; b < 10; ++b) {
    key |= ((unsigned)((x >> b) & 1)) << (3 * b + 2);
    key |= ((unsigned)((y >> b) & 1)) << (3 * b + 1);
    key |= ((unsigned)((z >> b) & 1)) << (3 * b + 0);
  }
  return key;
}

__device__ __forceinline__ unsigned int gcn_hilbert3(int x, int y, int z) {
  int X0 = x, X1 = y, X2 = z;
  for (int Q = 512; Q > 1; Q >>= 1) {
    int P = Q - 1;
    // i = 0: t == 0
    if (X0 & Q) X0 ^= P;
    // i = 1
    {
      int t = (X0 ^ X1) & P;
      if (X1 & Q) { X0 ^= P; } else { X0 ^= t; X1 ^= t; }
    }
    // i = 2
    {
      int t = (X0 ^ X2) & P;
      if (X2 & Q) { X0 ^= P; } else { X0 ^= t; X2 ^= t; }
    }
  }
  X1 ^= X0;
  X2 ^= X1;
  int t = 0;
  for (int Q = 512; Q > 1; Q >>= 1)
    if (X2 & Q) t ^= (Q - 1);
  X0 ^= t; X1 ^= t; X2 ^= t;
  unsigned int key = 0u;
#pragma unroll
  for (int b = 9; b >= 0; --b) {
    key = (key << 1) | (unsigned)((X0 >> b) & 1);
    key = (key << 1) | (unsigned)((X1 >> b) & 1);
    key = (key << 1) | (unsigned)((X2 >> b) & 1);
  }
  return key;
}

// ---------------- weight conversion ----------------
__global__ void gcn_cvt(const float* __restrict__ s, __half* __restrict__ d, int count) {
  int i = blockIdx.x * 256 + threadIdx.x;
  if (i < count) d[i] = __float2half(s[i]);
}

// Wfold[o][c] = sum_j W[o][4c+j]  (center columns: identical input across j)
__global__ void gcn_fold(const float* __restrict__ W, __half* __restrict__ Wf) {
  int i = blockIdx.x * 256 + threadIdx.x;   // 512*256
  int o = i >> 8, c = i & 255;
  float4 w = ((const float4*)W)[(size_t)o * 512 + c];
  Wf[i] = __float2half(w.x + w.y + w.z + w.w);
}

// ---------------- quantize prep ----------------
__global__ void gcn_minmax(const float* __restrict__ coords, float* __restrict__ mm) {
  __shared__ float slo[256], shi[256];
  int d = blockIdx.x, tid = threadIdx.x;
  float lo = 1e30f, hi = -1e30f;
  for (int i = tid; i < 4096; i += 256) {
    float v = coords[(size_t)d * 4096 + i];
    lo = fminf(lo, v);
    hi = fmaxf(hi, v);
  }
  slo[tid] = lo; shi[tid] = hi;
  __syncthreads();
  for (int s = 128; s > 0; s >>= 1) {
    if (tid < s) {
      slo[tid] = fminf(slo[tid], slo[tid + s]);
      shi[tid] = fmaxf(shi[tid], shi[tid + s]);
    }
    __syncthreads();
  }
  if (tid == 0) {
    mm[d] = slo[0];
    mm[6 + d] = 1023.0f / ((shi[0] - slo[0]) + 1e-6f);
  }
}

__global__ void gcn_keys(const float* __restrict__ coords, const float* __restrict__ mm,
                         unsigned long long* __restrict__ keys) {
  int idx = blockIdx.x * 256 + threadIdx.x;
  int b = idx >> 12, n = idx & 4095;
  const float* cb = coords + (size_t)b * 3 * 4096;
  int q0 = gcn_quant1(cb[n],        mm[b * 3 + 0], mm[6 + b * 3 + 0]);
  int q1 = gcn_quant1(cb[4096 + n], mm[b * 3 + 1], mm[6 + b * 3 + 1]);
  int q2 = gcn_quant1(cb[8192 + n], mm[b * 3 + 2], mm[6 + b * 3 + 2]);
  unsigned long long nn = (unsigned long long)(unsigned)n;
  size_t base = ((size_t)b * 4) * 4096 + n;
  keys[base]         = ((unsigned long long)gcn_morton3(q0, q1, q2) << 12) | nn;
  keys[base + 4096]  = ((unsigned long long)gcn_morton3(q1, q0, q2) << 12) | nn;  // qt = [1,0,2]
  keys[base + 8192]  = ((unsigned long long)gcn_hilbert3(q0, q1, q2) << 12) | nn;
  keys[base + 12288] = ((unsigned long long)gcn_hilbert3(q1, q0, q2) << 12) | nn;
}

// ---------------- bitonic sort (stable argsort replica) + window indices ----------------
__global__ __launch_bounds__(512) void gcn_sort(const unsigned long long* __restrict__ keys,
                                                int* __restrict__ inds) {
  __shared__ unsigned long long a[4096];
  int g = blockIdx.x, tid = threadIdx.x;
  for (int i = tid; i < 4096; i += 512) a[i] = keys[(size_t)g * 4096 + i];
  __syncthreads();
  for (int k = 2; k <= 4096; k <<= 1) {
    for (int j = k >> 1; j > 0; j >>= 1) {
      for (int t = tid; t < 2048; t += 512) {
        int i = 2 * t - (t & (j - 1));
        int p = i + j;
        bool up = (i & k) == 0;
        unsigned long long x = a[i], y = a[p];
        if ((x > y) == up) { a[i] = y; a[p] = x; }
      }
      __syncthreads();
    }
  }
  // window inds: pos = min(max(0,i-5)+kk, min(N,i+6)-1)
  for (int i = tid; i < 4096; i += 512) {
    int start = i - 5; if (start < 0) start = 0;
    int endm1 = i + 5; if (endm1 > 4095) endm1 = 4095;
#pragma unroll
    for (int kk = 0; kk < 10; ++kk) {
      int pos = start + kk; if (pos > endm1) pos = endm1;
      inds[((size_t)g * 4096 + i) * 10 + kk] = (int)(a[pos] & 0xFFFULL);
    }
  }
}

// ---------------- transpose (B,C,N) -> (B,N,C) ----------------
__global__ void gcn_transpose(const float* __restrict__ feats, float* __restrict__ fT) {
  __shared__ float t[32][33];
  int blk = blockIdx.x;
  int cb = blk & 7, nb = (blk >> 3) & 127, b = blk >> 10;
  int tx = threadIdx.x & 31, ty = threadIdx.x >> 5;
#pragma unroll
  for (int i = 0; i < 4; ++i) {
    int c = cb * 32 + ty + i * 8;
    t[ty + i * 8][tx] = feats[((size_t)(b * 256 + c) << 12) + nb * 32 + tx];
  }
  __syncthreads();
#pragma unroll
  for (int i = 0; i < 4; ++i) {
    int n = nb * 32 + ty + i * 8;
    fT[((size_t)((b << 12) + n)) * 256 + cb * 32 + tx] = t[tx][ty + i * 8];
  }
}

// ---------------- fused per-window kernel ----------------
// LDS map (bytes):
constexpr int SM_CF32 = 0;       // 256 f   (center fp32)
constexpr int SM_CF16 = 1024;    // 256 h   (center fp16)
constexpr int SM_XO   = 1536;    // 10 rows * 2064 B halves: x_diff, then attn-out (in place)
constexpr int SM_SC   = 22176;   // 400 f   (scores -> attn)
constexpr int SM_FCV  = 23776;   // 512 f   (center matvec + bias)
constexpr int SM_FU   = 25824;   // 10 rows * 2080 B floats (fused)
constexpr int SM_TOT  = 46624;   // < 64 KB -> up to 3 blocks/CU

template <int O2>
__global__ __launch_bounds__(256, 2) void gcn_window(
    const float* __restrict__ fT, const int* __restrict__ inds,
    const __half* __restrict__ Wl16, const __half* __restrict__ Wf16,
    const float* __restrict__ blin, const __half* __restrict__ Wc16,
    float* __restrict__ hmax, float* __restrict__ S1, float* __restrict__ S2,
    int p0, int p1, int p2, int p3) {
  __shared__ __align__(16) char smem[SM_TOT];
  float*  cf32 = (float*)(smem + SM_CF32);
  __half* cf16 = (__half*)(smem + SM_CF16);
  float*  sc   = (float*)(smem + SM_SC);
  float*  fcv  = (float*)(smem + SM_FCV);
  float*  fu   = (float*)(smem + SM_FU);

  const int tid  = threadIdx.x;
  const int lane = tid & 63, wave = tid >> 6;
  const int tl   = lane & 15, og = lane >> 4;
  const int b = blockIdx.x >> 12, n = blockIdx.x & 4095;

  // ---- P0: center features ----
  {
    float v = fT[((size_t)(b << 12) + n) * 256 + tid];
    cf32[tid] = v;
    cf16[tid] = __float2half(v);
  }
  __syncthreads();

  // ---- P1: gather neighbors, build x_diff fp16 (wave w handles j-slot w) ----
  {
    int j = wave;
    int m = (j == 0) ? p0 : (j == 1) ? p1 : (j == 2) ? p2 : p3;
    const float4 cv = ((const float4*)cf32)[lane];
    const int* indrow = inds + ((size_t)((b * 4 + m) << 12) + n) * 10;
    for (int kk = 0; kk < 10; ++kk) {
      int idx = indrow[kk];
      const float4 v = ((const float4*)(fT + ((size_t)(b << 12) + idx) * 256))[lane];
      __half* row = (__half*)(smem + SM_XO + kk * 2064);
      int base = 16 * lane + j;   // half index = 4*c + j, c = 4*lane + i
      row[base + 0]  = __float2half(v.x - cv.x);
      row[base + 4]  = __float2half(v.y - cv.y);
      row[base + 8]  = __float2half(v.z - cv.z);
      row[base + 12] = __float2half(v.w - cv.w);
    }
  }
  __syncthreads();

  // ---- P2: attention scores, heads 4..7 only (heads 0..3 are identity) ----
  for (int t = tid; t < 400; t += 256) {
    int hd = t / 100;
    int r = t - hd * 100;
    int i = r / 10;
    int jj = r - (r / 10) * 10;
    const __half2* ri = (const __half2*)(smem + SM_XO + i * 2064);
    const __half2* rj = (const __half2*)(smem + SM_XO + jj * 2064);
    float a = 0.f;
    for (int pp = 0; pp < 128; ++pp) {
      float2 x = __half22float2(ri[hd * 128 + pp]);
      float2 y = __half22float2(rj[hd * 128 + pp]);
      a = fmaf(x.x, y.x, a);
      a = fmaf(x.y, y.y, a);
    }
    sc[t] = a * 0.0625f;   // / sqrt(256)
  }
  __syncthreads();

  // ---- P3: softmax over j ----
  if (tid < 40) {
    float s[10];
    float m = -1e30f;
#pragma unroll
    for (int j = 0; j < 10; ++j) { s[j] = sc[tid * 10 + j]; m = fmaxf(m, s[j]); }
    float sum = 0.f;
#pragma unroll
    for (int j = 0; j < 10; ++j) { s[j] = expf(s[j] - m); sum += s[j]; }
    float inv = 1.0f / sum;
#pragma unroll
    for (int j = 0; j < 10; ++j) sc[tid * 10 + j] = s[j] * inv;
  }
  __syncthreads();

  // ---- P4: out = attn @ x_diff, column-wise in place (each thread owns columns) ----
  for (int p = tid; p < 512; p += 256) {
    int hd = p >> 7;
    float2 xv[10];
#pragma unroll
    for (int j = 0; j < 10; ++j)
      xv[j] = __half22float2(*(const __half2*)(smem + SM_XO + j * 2064 + p * 4));
#pragma unroll
    for (int kk = 0; kk < 10; ++kk) {
      const float* arow = sc + (hd * 10 + kk) * 10;
      float ax = 0.f, ay = 0.f;
#pragma unroll
      for (int j = 0; j < 10; ++j) {
        float w = arow[j];
        ax = fmaf(w, xv[j].x, ax);
        ay = fmaf(w, xv[j].y, ay);
      }
      *(__half2*)(smem + SM_XO + kk * 2064 + p * 4) = __floats2half2_rn(ax, ay);
    }
  }

  // ---- P5: center matvec fc[o] = Wfold[o,:] . center16 + b_lin[o] ----
  {
    const __half2* cp  = (const __half2*)cf16;
    const __half2* Wf2 = (const __half2*)Wf16;
#pragma unroll 1
    for (int q = 0; q < 4; ++q) {
      int obase = (wave * 4 + q) * 32 + og * 8;
      float acc[8];
#pragma unroll
      for (int i = 0; i < 8; ++i) acc[i] = 0.f;
      for (int pi = 0; pi < 8; ++pi) {
        int p = pi * 16 + tl;
        float2 c2 = __half22float2(cp[p]);
#pragma unroll
        for (int i = 0; i < 8; ++i) {
          float2 w = __half22float2(Wf2[(size_t)(obase + i) * 128 + p]);
          acc[i] = fmaf(w.x, c2.x, fmaf(w.y, c2.y, acc[i]));
        }
      }
#pragma unroll
      for (int i = 0; i < 8; ++i) {
        float v = acc[i];
        v += __shfl_xor(v, 1); v += __shfl_xor(v, 2);
        v += __shfl_xor(v, 4); v += __shfl_xor(v, 8);
        acc[i] = v;
      }
      if (tl == 0) {
#pragma unroll
        for (int i = 0; i < 8; ++i) fcv[obase + i] = acc[i] + blin[obase + i];
      }
    }
  }
  __syncthreads();   // covers P4 out writes + P5 fcv

  // ---- P6: fused[kk][o] = out_diff[kk,:] . Wdiff[o,:] + fc[o] ----
  {
    const __half2* Wl2 = (const __half2*)Wl16;
#pragma unroll 1
    for (int q = 0; q < 4; ++q) {
      int obase = (wave * 4 + q) * 32 + og * 8;
      float acc[8][10];
#pragma unroll
      for (int i = 0; i < 8; ++i)
#pragma unroll
        for (int kk = 0; kk < 10; ++kk) acc[i][kk] = 0.f;
#pragma unroll 2
      for (int pi = 0; pi < 32; ++pi) {
        int p = pi * 16 + tl;
        float2 xv[10];
#pragma unroll
        for (int kk = 0; kk < 10; ++kk)
          xv[kk] = __half22float2(*(const __half2*)(smem + SM_XO + kk * 2064 + p * 4));
#pragma unroll
        for (int i = 0; i < 8; ++i) {
          float2 w = __half22float2(Wl2[(size_t)(obase + i) * 1024 + 512 + p]);
#pragma unroll
          for (int kk = 0; kk < 10; ++kk)
            acc[i][kk] = fmaf(w.x, xv[kk].x, fmaf(w.y, xv[kk].y, acc[i][kk]));
        }
      }
#pragma unroll
      for (int i = 0; i < 8; ++i)
#pragma unroll
        for (int kk = 0; kk < 10; ++kk) {
          float v = acc[i][kk];
          v += __shfl_xor(v, 1); v += __shfl_xor(v, 2);
          v += __shfl_xor(v, 4); v += __shfl_xor(v, 8);
          acc[i][kk] = v;
        }
      if (tl == 0) {
#pragma unroll
        for (int i = 0; i < 8; ++i) {
          float fc = fcv[obase + i];
#pragma unroll
          for (int kk = 0; kk < 10; ++kk)
            fu[kk * 520 + obase + i] = acc[i][kk] + fc;
        }
      }
    }
  }
  __syncthreads();

  // ---- P7: conv h = Wc . fused^T, then max_k + stats (norm/lrelu commute with max) ----
  {
    const __half2* Wc2 = (const __half2*)Wc16;
    constexpr int QB = O2 / 128;   // 2 for O2=256, 4 for O2=512
    const int slot = blockIdx.x & 63;
#pragma unroll 1
    for (int q = 0; q < QB; ++q) {
      int obase = (wave * QB + q) * 32 + og * 8;
      float acc[8][10];
#pragma unroll
      for (int i = 0; i < 8; ++i)
#pragma unroll
        for (int kk = 0; kk < 10; ++kk) acc[i][kk] = 0.f;
#pragma unroll 2
      for (int pi = 0; pi < 16; ++pi) {
        int p = pi * 16 + tl;
        float2 fv[10];
#pragma unroll
        for (int kk = 0; kk < 10; ++kk)
          fv[kk] = *(const float2*)(smem + SM_FU + kk * 2080 + p * 8);
#pragma unroll
        for (int i = 0; i < 8; ++i) {
          float2 w = __half22float2(Wc2[(size_t)(obase + i) * 256 + p]);
#pragma unroll
          for (int kk = 0; kk < 10; ++kk)
            acc[i][kk] = fmaf(w.x, fv[kk].x, fmaf(w.y, fv[kk].y, acc[i][kk]));
        }
      }
#pragma unroll
      for (int i = 0; i < 8; ++i)
#pragma unroll
        for (int kk = 0; kk < 10; ++kk) {
          float v = acc[i][kk];
          v += __shfl_xor(v, 1); v += __shfl_xor(v, 2);
          v += __shfl_xor(v, 4); v += __shfl_xor(v, 8);
          acc[i][kk] = v;
        }
      if (tl == 0) {
#pragma unroll
        for (int i = 0; i < 8; ++i) {
          int o2 = obase + i;
          float mx = -1e30f, s1 = 0.f, s2 = 0.f;
#pragma unroll
          for (int kk = 0; kk < 10; ++kk) {
            float v = acc[i][kk];
            mx = fmaxf(mx, v);
            s1 += v;
            s2 = fmaf(v, v, s2);
          }
          hmax[((size_t)(b * O2 + o2) << 12) + n] = mx;
          atomicAdd(&S1[(size_t)(slot * 2 + b) * O2 + o2], s1);
          atomicAdd(&S2[(size_t)(slot * 2 + b) * O2 + o2], s2);
        }
      }
    }
  }
}

// ---------------- stats reduce: slots -> mu, 1/sigma ----------------
__global__ void gcn_stats(const float* __restrict__ S1, const float* __restrict__ S2,
                          float* __restrict__ mu, float* __restrict__ rs,
                          int O2, float invNK) {
  int t = threadIdx.x;
  if (t < 2 * O2) {
    float s1 = 0.f, s2 = 0.f;
    for (int s = 0; s < 64; ++s) {
      s1 += S1[(size_t)s * 2 * O2 + t];
      s2 += S2[(size_t)s * 2 * O2 + t];
    }
    float m = s1 * invNK;
    float var = s2 * invNK - m * m;
    mu[t] = m;
    rs[t] = 1.0f / sqrtf(var + 1e-5f);
  }
}

// ---------------- normalize + lrelu; optional transposed copy ----------------
__global__ void gcn_norm(const float* __restrict__ src, const float* __restrict__ mu,
                         const float* __restrict__ rs, float* __restrict__ fN,
                         float* __restrict__ fT) {
  int idx = blockIdx.x * 256 + threadIdx.x;
  int n = idx & 4095;
  int bo = idx >> 12;
  float v = (src[idx] - mu[bo]) * rs[bo];
  v = v > 0.f ? v : 0.2f * v;
  fN[idx] = v;
  if (fT != nullptr) {       // layer-1 only: also (B,N,256) layout for next gather
    int o = bo & 255;
    int b = bo >> 8;
    fT[((size_t)((b << 12) + n)) * 256 + o] = v;
  }
}

// ---------------- final conv: h3 = W_conv3 . concat(feats, f1, f2) ----------------
__global__ __launch_bounds__(256, 2) void gcn_final_conv(
    const float* __restrict__ feats, const float* __restrict__ f1N,
    const float* __restrict__ f2N, const float* __restrict__ Wc3,
    float* __restrict__ h3, float* __restrict__ S1, float* __restrict__ S2) {
  __shared__ float ftile[128 * 64];
  int x = blockIdx.x;
  int ob = x & 3, nb = (x >> 2) & 63, b = x >> 8;
  int lane = threadIdx.x & 63, wave = threadIdx.x >> 6;
  int n0 = nb * 64, o0 = ob * 64;
  float acc[16];
#pragma unroll
  for (int i = 0; i < 16; ++i) acc[i] = 0.f;
  for (int ct = 0; ct < 8; ++ct) {
    int cg0 = ct * 128;
    __syncthreads();
    for (int idx = threadIdx.x; idx < 8192; idx += 256) {
      int ccc = idx >> 6, ln = idx & 63;
      int c = cg0 + ccc;
      float v;
      if (c < 256)      v = feats[((size_t)(b * 256 + c) << 12) + n0 + ln];
      else if (c < 512) v = f1N[((size_t)(b * 256 + (c - 256)) << 12) + n0 + ln];
      else              v = f2N[((size_t)(b * 512 + (c - 512)) << 12) + n0 + ln];
      ftile[ccc * 64 + ln] = v;
    }
    __syncthreads();
    for (int c = 0; c < 128; ++c) {
      float fv = ftile[c * 64 + lane];
#pragma unroll
      for (int oi = 0; oi < 16; ++oi) {
        int o = o0 + wave * 16 + oi;
        acc[oi] = fmaf(Wc3[(size_t)o * 1024 + cg0 + c], fv, acc[oi]);
      }
    }
  }
  int slot = nb;
#pragma unroll
  for (int oi = 0; oi < 16; ++oi) {
    int o = o0 + wave * 16 + oi;
    float v = acc[oi];
    h3[((size_t)(b * 256 + o) << 12) + n0 + lane] = v;
    float s1 = v, s2 = v * v;
#pragma unroll
    for (int m = 1; m < 64; m <<= 1) {
      s1 += __shfl_xor(s1, m);
      s2 += __shfl_xor(s2, m);
    }
    if (lane == 0) {
      atomicAdd(&S1[(size_t)(slot * 2 + b) * 256 + o], s1);
      atomicAdd(&S2[(size_t)(slot * 2 + b) * 256 + o], s2);
    }
  }
}

// ---------------- launch ----------------
extern "C" void kernel_launch(void* const* d_in, const int* in_sizes, int n_in,
                              void* d_out, int out_size, void* d_ws, size_t ws_size,
                              hipStream_t stream) {
  (void)in_sizes; (void)n_in; (void)out_size; (void)ws_size;
  const float* coords  = (const float*)d_in[0];
  const float* feats   = (const float*)d_in[1];
  const float* W_lin1  = (const float*)d_in[2];
  const float* b_lin1  = (const float*)d_in[3];
  const float* W_lin2  = (const float*)d_in[4];
  const float* b_lin2  = (const float*)d_in[5];
  const float* W_conv1 = (const float*)d_in[6];
  const float* W_conv2 = (const float*)d_in[7];
  const float* W_conv3 = (const float*)d_in[8];
  char* ws = (char*)d_ws;

  float* F_MM    = (float*)(ws + OFF_MM);
  unsigned long long* KEYS = (unsigned long long*)(ws + OFF_KEYS);
  int* INDS      = (int*)(ws + OFF_INDS);
  __half* WL1H   = (__half*)(ws + OFF_WL1H);
  __half* WL2H   = (__half*)(ws + OFF_WL2H);
  __half* WF1    = (__half*)(ws + OFF_WF1);
  __half* WF2    = (__half*)(ws + OFF_WF2);
  __half* WC1H   = (__half*)(ws + OFF_WC1H);
  __half* WC2H   = (__half*)(ws + OFF_WC2H);
  float* FEATST  = (float*)(ws + OFF_FEATST);
  float* F1T     = (float*)(ws + OFF_F1T);
  float* F1N     = (float*)(ws + OFF_F1N);
  float* F2N     = (float*)(ws + OFF_F2N);
  float* HMAX1   = (float*)(ws + OFF_HMAX1);
  float* HMAX2   = (float*)(ws + OFF_HMAX2);
  float* H3      = (float*)(ws + OFF_H3);

  // zero the atomic stats accumulators (ws is poisoned each call)
  (void)hipMemsetAsync(ws + OFF_S1a, 0, STATS_BYTES, stream);

  // weight conversion
  gcn_cvt<<<4096, 256, 0, stream>>>(W_lin1, WL1H, 512 * 2048);
  gcn_cvt<<<4096, 256, 0, stream>>>(W_lin2, WL2H, 512 * 2048);
  gcn_cvt<<<512,  256, 0, stream>>>(W_conv1, WC1H, 256 * 512);
  gcn_cvt<<<1024, 256, 0, stream>>>(W_conv2, WC2H, 512 * 512);
  gcn_fold<<<512, 256, 0, stream>>>(W_lin1, WF1);
  gcn_fold<<<512, 256, 0, stream>>>(W_lin2, WF2);

  // keys + sort + windows
  gcn_minmax<<<6, 256, 0, stream>>>(coords, F_MM);
  gcn_keys<<<32, 256, 0, stream>>>(coords, F_MM, KEYS);
  gcn_sort<<<8, 512, 0, stream>>>(KEYS, INDS);
  gcn_transpose<<<2048, 256, 0, stream>>>(feats, FEATST);

  // layer 1 (perm1 = [2,0,3,1])
  gcn_window<256><<<8192, 256, 0, stream>>>(
      FEATST, INDS, WL1H, WF1, b_lin1, WC1H,
      HMAX1, (float*)(ws + OFF_S1a), (float*)(ws + OFF_S2a), 2, 0, 3, 1);
  gcn_stats<<<1, 1024, 0, stream>>>((float*)(ws + OFF_S1a), (float*)(ws + OFF_S2a),
                                    (float*)(ws + OFF_MU1), (float*)(ws + OFF_RS1),
                                    256, 1.0f / 40960.0f);
  gcn_norm<<<8192, 256, 0, stream>>>(HMAX1, (float*)(ws + OFF_MU1), (float*)(ws + OFF_RS1),
                                     F1N, F1T);

  // layer 2 (perm2 = [1,3,0,2])
  gcn_window<512><<<8192, 256, 0, stream>>>(
      F1T, INDS, WL2H, WF2, b_lin2, WC2H,
      HMAX2, (float*)(ws + OFF_S1b), (float*)(ws + OFF_S2b), 1, 3, 0, 2);
  gcn_stats<<<1, 1024, 0, stream>>>((float*)(ws + OFF_S1b), (float*)(ws + OFF_S2b),
                                    (float*)(ws + OFF_MU2), (float*)(ws + OFF_RS2),
                                    512, 1.0f / 40960.0f);
  gcn_norm<<<16384, 256, 0, stream>>>(HMAX2, (float*)(ws + OFF_MU2), (float*)(ws + OFF_RS2),
                                      F2N, nullptr);

  // final conv + norm
  gcn_final_conv<<<512, 256, 0, stream>>>(feats, F1N, F2N, W_conv3,
                                          H3, (float*)(ws + OFF_S1f), (float*)(ws + OFF_S2f));
  gcn_stats<<<1, 1024, 0, stream>>>((float*)(ws + OFF_S1f), (float*)(ws + OFF_S2f),
                                    (float*)(ws + OFF_MU3), (float*)(ws + OFF_RS3),
                                    256, 1.0f / 4096.0f);
  gcn_norm<<<8192, 256, 0, stream>>>(H3, (float*)(ws + OFF_MU3), (float*)(ws + OFF_RS3),
                                     (float*)d_out, nullptr);
}

// Round 2
// 2151.188 us; speedup vs baseline: 2.2641x; 2.2641x over previous
//
#include <hip/hip_runtime.h>
#include <hip/hip_fp16.h>

// =====================================================================
// GCN pipeline on MI355X, round 1: MFMA window kernel.
//  - P6/P7 GEMMs via v_mfma_f32_16x16x32_f16, weights pre-packed fragment-major
//  - P2 attention scores via MFMA (D = A.A^T per head, a==b frag)
//  - x_diff column layout head-major: d = head*256 + j*64 + clow
//  - norm/lrelu commute with max_k -> only max + atomic stats kept
// =====================================================================

typedef _Float16 half8v __attribute__((ext_vector_type(8)));
typedef _Float16 half2v __attribute__((ext_vector_type(2)));
typedef float    float4v __attribute__((ext_vector_type(4)));

// ---------------- workspace layout (bytes) ----------------
constexpr size_t OFF_S1a    = 0;
constexpr size_t OFF_S2a    = OFF_S1a + 64ull*2*256*4;
constexpr size_t OFF_S1b    = OFF_S2a + 64ull*2*256*4;
constexpr size_t OFF_S2b    = OFF_S1b + 64ull*2*512*4;
constexpr size_t OFF_S1f    = OFF_S2b + 64ull*2*512*4;
constexpr size_t OFF_S2f    = OFF_S1f + 64ull*2*256*4;
constexpr size_t STATS_BYTES= OFF_S2f + 64ull*2*256*4;      // zeroed each call
constexpr size_t OFF_MU1    = STATS_BYTES;
constexpr size_t OFF_RS1    = OFF_MU1 + 2048;
constexpr size_t OFF_MU2    = OFF_RS1 + 2048;
constexpr size_t OFF_RS2    = OFF_MU2 + 4096;
constexpr size_t OFF_MU3    = OFF_RS2 + 4096;
constexpr size_t OFF_RS3    = OFF_MU3 + 2048;
constexpr size_t OFF_MM     = OFF_RS3 + 2048;               // 12 floats
constexpr size_t OFF_KEYS   = OFF_MM + 256;
constexpr size_t OFF_INDS   = OFF_KEYS + 8ull*4096*8;
constexpr size_t OFF_PK6_1  = OFF_INDS + 8ull*4096*10*4;    // 1 MB packed Wdiff1
constexpr size_t OFF_PK6_2  = OFF_PK6_1 + 512ull*2048*2;    // 1 MB packed Wdiff2
constexpr size_t OFF_WF1    = OFF_PK6_2 + 512ull*2048*2;
constexpr size_t OFF_WF2    = OFF_WF1  + 512ull*256*2;
constexpr size_t OFF_PK7_1  = OFF_WF2  + 512ull*256*2;      // 256 KB packed Wc1
constexpr size_t OFF_PK7_2  = OFF_PK7_1 + 256ull*512*2;     // 512 KB packed Wc2
constexpr size_t OFF_FEATST = OFF_PK7_2 + 512ull*512*2;     // (B,N,256) fp32
constexpr size_t OFF_F1T    = OFF_FEATST + 2ull*4096*256*4; // (B,N,256)
constexpr size_t OFF_F2N    = OFF_F1T   + 2ull*4096*256*4;  // (B,512,N)
constexpr size_t OFF_HMAX1  = OFF_F2N   + 2ull*4096*512*4;  // (B,256,N)
constexpr size_t OFF_HMAX2  = OFF_HMAX1 + 2ull*4096*256*4;  // (B,512,N)
constexpr size_t WS_NEED    = OFF_HMAX2 + 2ull*4096*512*4;
// lifetime-disjoint aliases:
constexpr size_t OFF_F1N    = OFF_FEATST;   // featsT dead after layer-1 window
constexpr size_t OFF_H3     = OFF_HMAX1;    // hmax1 dead after normalize1

// ---------------- helpers ----------------
__device__ __forceinline__ int gcn_quant1(float c, float cmin, float scale) {
  float q = floorf(__fmul_rn(__fsub_rn(c, cmin), scale));
  q = fminf(fmaxf(q, 0.0f), 1023.0f);
  return (int)q;
}

__device__ __forceinline__ unsigned int gcn_morton3(int x, int y, int z) {
  unsigned int key = 0u;
#pragma unroll
  for (int b = 0; b < 10; ++b) {
    key |= ((unsigned)((x >> b) & 1)) << (3 * b + 2);
    key |= ((unsigned)((y >> b) & 1)) << (3 * b + 1);
    key |= ((unsigned)((z >> b) & 1)) << (3 * b + 0);
  }
  return key;
}

__device__ __forceinline__ unsigned int gcn_hilbert3(int x, int y, int z) {
  int X0 = x, X1 = y, X2 = z;
  for (int Q = 512; Q > 1; Q >>= 1) {
    int P = Q - 1;
    if (X0 & Q) X0 ^= P;
    {
      int t = (X0 ^ X1) & P;
      if (X1 & Q) { X0 ^= P; } else { X0 ^= t; X1 ^= t; }
    }
    {
      int t = (X0 ^ X2) & P;
      if (X2 & Q) { X0 ^= P; } else { X0 ^= t; X2 ^= t; }
    }
  }
  X1 ^= X0;
  X2 ^= X1;
  int t = 0;
  for (int Q = 512; Q > 1; Q >>= 1)
    if (X2 & Q) t ^= (Q - 1);
  X0 ^= t; X1 ^= t; X2 ^= t;
  unsigned int key = 0u;
#pragma unroll
  for (int b = 9; b >= 0; --b) {
    key = (key << 1) | (unsigned)((X0 >> b) & 1);
    key = (key << 1) | (unsigned)((X1 >> b) & 1);
    key = (key << 1) | (unsigned)((X2 >> b) & 1);
  }
  return key;
}

// ---------------- weight packing ----------------
// Wfold[o][c] = sum_j W[o][4c+j] (center cols identical across j)
__global__ void gcn_fold(const float* __restrict__ W, __half* __restrict__ Wf) {
  int i = blockIdx.x * 256 + threadIdx.x;   // 512*256
  int o = i >> 8, c = i & 255;
  float4 w = ((const float4*)W)[(size_t)o * 512 + c];
  Wf[i] = __float2half(w.x + w.y + w.z + w.w);
}

// P6 B-fragment pack: frag f=(nt*32+ks)*64+lane holds 8 halves
// B[k=ks*32+q*8+j8][n=nt*16+tl], column layout d = 256*head + 64*jslot + clow
__global__ void gcn_pack6(const float* __restrict__ W, _Float16* __restrict__ P) {
  int i = blockIdx.x * 256 + threadIdx.x;   // 65536
  int lane = i & 63, ks = (i >> 6) & 31, nt = i >> 11;
  int tl = lane & 15, q = lane >> 4;
  int o = nt * 16 + tl;
  _Float16 tmp[8];
#pragma unroll
  for (int j8 = 0; j8 < 8; ++j8) {
    int d = ks * 32 + q * 8 + j8;
    int head = d >> 8, jj = (d >> 6) & 3, cl = d & 63;
    int col = 1024 + 256 * head + 4 * cl + jj;  // original x column (diff part)
    tmp[j8] = (_Float16)W[(size_t)o * 2048 + col];
  }
  *(half8v*)(P + (size_t)i * 8) = *(half8v*)tmp;
}

// P7 B-fragment pack: frag f=(nt*16+ks)*64+lane, B[k=c2][n=o2]=Wc[o2][c2]
__global__ void gcn_pack7(const float* __restrict__ W, _Float16* __restrict__ P) {
  int i = blockIdx.x * 256 + threadIdx.x;   // O2*64
  int lane = i & 63, ks = (i >> 6) & 15, nt = i >> 10;
  int tl = lane & 15, q = lane >> 4;
  int o2 = nt * 16 + tl;
  int c2 = ks * 32 + q * 8;
  _Float16 tmp[8];
#pragma unroll
  for (int j8 = 0; j8 < 8; ++j8)
    tmp[j8] = (_Float16)W[(size_t)o2 * 512 + c2 + j8];
  *(half8v*)(P + (size_t)i * 8) = *(half8v*)tmp;
}

// ---------------- quantize prep ----------------
__global__ void gcn_minmax(const float* __restrict__ coords, float* __restrict__ mm) {
  __shared__ float slo[256], shi[256];
  int d = blockIdx.x, tid = threadIdx.x;
  float lo = 1e30f, hi = -1e30f;
  for (int i = tid; i < 4096; i += 256) {
    float v = coords[(size_t)d * 4096 + i];
    lo = fminf(lo, v);
    hi = fmaxf(hi, v);
  }
  slo[tid] = lo; shi[tid] = hi;
  __syncthreads();
  for (int s = 128; s > 0; s >>= 1) {
    if (tid < s) {
      slo[tid] = fminf(slo[tid], slo[tid + s]);
      shi[tid] = fmaxf(shi[tid], shi[tid + s]);
    }
    __syncthreads();
  }
  if (tid == 0) {
    mm[d] = slo[0];
    mm[6 + d] = 1023.0f / ((shi[0] - slo[0]) + 1e-6f);
  }
}

__global__ void gcn_keys(const float* __restrict__ coords, const float* __restrict__ mm,
                         unsigned long long* __restrict__ keys) {
  int idx = blockIdx.x * 256 + threadIdx.x;
  int b = idx >> 12, n = idx & 4095;
  const float* cb = coords + (size_t)b * 3 * 4096;
  int q0 = gcn_quant1(cb[n],        mm[b * 3 + 0], mm[6 + b * 3 + 0]);
  int q1 = gcn_quant1(cb[4096 + n], mm[b * 3 + 1], mm[6 + b * 3 + 1]);
  int q2 = gcn_quant1(cb[8192 + n], mm[b * 3 + 2], mm[6 + b * 3 + 2]);
  unsigned long long nn = (unsigned long long)(unsigned)n;
  size_t base = ((size_t)b * 4) * 4096 + n;
  keys[base]         = ((unsigned long long)gcn_morton3(q0, q1, q2) << 12) | nn;
  keys[base + 4096]  = ((unsigned long long)gcn_morton3(q1, q0, q2) << 12) | nn;
  keys[base + 8192]  = ((unsigned long long)gcn_hilbert3(q0, q1, q2) << 12) | nn;
  keys[base + 12288] = ((unsigned long long)gcn_hilbert3(q1, q0, q2) << 12) | nn;
}

// ---------------- bitonic sort (stable argsort replica) + windows ----------------
__global__ __launch_bounds__(512) void gcn_sort(const unsigned long long* __restrict__ keys,
                                                int* __restrict__ inds) {
  __shared__ unsigned long long a[4096];
  int g = blockIdx.x, tid = threadIdx.x;
  for (int i = tid; i < 4096; i += 512) a[i] = keys[(size_t)g * 4096 + i];
  __syncthreads();
  for (int k = 2; k <= 4096; k <<= 1) {
    for (int j = k >> 1; j > 0; j >>= 1) {
      for (int t = tid; t < 2048; t += 512) {
        int i = 2 * t - (t & (j - 1));
        int p = i + j;
        bool up = (i & k) == 0;
        unsigned long long x = a[i], y = a[p];
        if ((x > y) == up) { a[i] = y; a[p] = x; }
      }
      __syncthreads();
    }
  }
  for (int i = tid; i < 4096; i += 512) {
    int start = i - 5; if (start < 0) start = 0;
    int endm1 = i + 5; if (endm1 > 4095) endm1 = 4095;
#pragma unroll
    for (int kk = 0; kk < 10; ++kk) {
      int pos = start + kk; if (pos > endm1) pos = endm1;
      inds[((size_t)g * 4096 + i) * 10 + kk] = (int)(a[pos] & 0xFFFULL);
    }
  }
}

// ---------------- transpose (B,C,N) -> (B,N,C) ----------------
__global__ void gcn_transpose(const float* __restrict__ feats, float* __restrict__ fT) {
  __shared__ float t[32][33];
  int blk = blockIdx.x;
  int cb = blk & 7, nb = (blk >> 3) & 127, b = blk >> 10;
  int tx = threadIdx.x & 31, ty = threadIdx.x >> 5;
#pragma unroll
  for (int i = 0; i < 4; ++i) {
    int c = cb * 32 + ty + i * 8;
    t[ty + i * 8][tx] = feats[((size_t)(b * 256 + c) << 12) + nb * 32 + tx];
  }
  __syncthreads();
#pragma unroll
  for (int i = 0; i < 4; ++i) {
    int n = nb * 32 + ty + i * 8;
    fT[((size_t)((b << 12) + n)) * 256 + cb * 32 + tx] = t[tx][ty + i * 8];
  }
}

// ---------------- fused per-window MFMA kernel ----------------
// LDS map (bytes):
constexpr int SM_CF16 = 0;       // 256 halves (center fp16)
constexpr int SM_SC   = 512;     // 400 f (scores -> attn)
constexpr int SM_FCV  = 2112;    // 512 f (center matvec + bias)
constexpr int SM_XD   = 4160;    // 16 rows * 2064 B halves (x_diff -> out, in place)
constexpr int SM_FU   = 37184;   // 16 rows * 1040 B halves (fused fp16)
constexpr int SM_TOT  = 53824;   // -> 3 blocks/CU

template <int O2>
__global__ __launch_bounds__(256, 3) void gcn_window(
    const float* __restrict__ fT, const int* __restrict__ inds,
    const _Float16* __restrict__ PK6, const __half* __restrict__ Wf16,
    const float* __restrict__ blin, const _Float16* __restrict__ PK7,
    float* __restrict__ hmax, float* __restrict__ S1, float* __restrict__ S2,
    int p0, int p1, int p2, int p3) {
  __shared__ __align__(16) char smem[SM_TOT];
  __half* cf16 = (__half*)(smem + SM_CF16);
  float*  sc   = (float*)(smem + SM_SC);
  float*  fcv  = (float*)(smem + SM_FCV);

  const int tid  = threadIdx.x;
  const int lane = tid & 63, wave = tid >> 6;
  const int tl   = lane & 15, q = lane >> 4;
  const int b = blockIdx.x >> 12, n = blockIdx.x & 4095;
  const float* fTb = fT + ((size_t)(b << 12)) * 256;

  // ---- P0: center fp16 (for P5) ----
  cf16[tid] = __float2half(fTb[(size_t)n * 256 + tid]);

  // ---- P1: gather + diff, head-major layout d = q*256 + j*64 + 4*tl + i ----
  {
    const int j = wave;
    const int m = (j == 0) ? p0 : (j == 1) ? p1 : (j == 2) ? p2 : p3;
    const float4 cv = ((const float4*)(fTb + (size_t)n * 256))[lane];
    const int* indrow = inds + ((size_t)((b * 4 + m) << 12) + n) * 10;
    const int byteoff = q * 512 + j * 128 + tl * 8;
    for (int kk = 0; kk < 10; ++kk) {
      int idx = indrow[kk];
      const float4 v = ((const float4*)(fTb + (size_t)idx * 256))[lane];
      union { __half2 h2[2]; uint2 u; } pk;
      pk.h2[0] = __floats2half2_rn(v.x - cv.x, v.y - cv.y);
      pk.h2[1] = __floats2half2_rn(v.z - cv.z, v.w - cv.w);
      *(uint2*)(smem + SM_XD + kk * 2064 + byteoff) = pk.u;
    }
  }
  __syncthreads();

  // ---- P2: attention scores via MFMA: wave w = head w, D = X.X^T ----
  {
    float4v acc = {0.f, 0.f, 0.f, 0.f};
#pragma unroll
    for (int ks = 0; ks < 8; ++ks) {
      half8v a = *(const half8v*)(smem + SM_XD + tl * 2064 + wave * 512 + ks * 64 + q * 16);
      acc = __builtin_amdgcn_mfma_f32_16x16x32_f16(a, a, acc, 0, 0, 0);
    }
#pragma unroll
    for (int r = 0; r < 4; ++r) {
      int row = q * 4 + r;
      if (row < 10 && tl < 10)
        sc[wave * 100 + row * 10 + tl] = acc[r] * 0.0625f;   // / sqrt(256)
    }
  }
  __syncthreads();

  // ---- P3: softmax over j ----
  if (tid < 40) {
    float s[10];
    float m = -1e30f;
#pragma unroll
    for (int j = 0; j < 10; ++j) { s[j] = sc[tid * 10 + j]; m = fmaxf(m, s[j]); }
    float sum = 0.f;
#pragma unroll
    for (int j = 0; j < 10; ++j) { s[j] = expf(s[j] - m); sum += s[j]; }
    float inv = 1.0f / sum;
#pragma unroll
    for (int j = 0; j < 10; ++j) sc[tid * 10 + j] = s[j] * inv;
  }
  __syncthreads();

  // ---- P4: out = attn @ x_diff, column-owned in place ----
  for (int p = tid; p < 512; p += 256) {
    int hd = p >> 7;
    float2 xv[10];
#pragma unroll
    for (int j = 0; j < 10; ++j)
      xv[j] = __half22float2(*(const __half2*)(smem + SM_XD + j * 2064 + p * 4));
#pragma unroll
    for (int kk = 0; kk < 10; ++kk) {
      const float* arow = sc + (hd * 10 + kk) * 10;
      float ax = 0.f, ay = 0.f;
#pragma unroll
      for (int j = 0; j < 10; ++j) {
        float w = arow[j];
        ax = fmaf(w, xv[j].x, ax);
        ay = fmaf(w, xv[j].y, ay);
      }
      *(__half2*)(smem + SM_XD + kk * 2064 + p * 4) = __floats2half2_rn(ax, ay);
    }
  }

  // ---- P5: center matvec fcv[o] = Wfold[o,:] . center16 + b_lin[o] (fdot2) ----
  {
    const half2v* cp  = (const half2v*)cf16;
    const half2v* Wf2 = (const half2v*)Wf16;
#pragma unroll 1
    for (int qq = 0; qq < 4; ++qq) {
      int obase = (wave * 4 + qq) * 32 + q * 8;
      float acc[8];
#pragma unroll
      for (int i = 0; i < 8; ++i) acc[i] = 0.f;
      for (int pi = 0; pi < 8; ++pi) {
        int p = pi * 16 + tl;
        half2v c2 = cp[p];
#pragma unroll
        for (int i = 0; i < 8; ++i)
          acc[i] = __builtin_amdgcn_fdot2(Wf2[(size_t)(obase + i) * 128 + p], c2, acc[i], false);
      }
#pragma unroll
      for (int i = 0; i < 8; ++i) {
        float v = acc[i];
        v += __shfl_xor(v, 1); v += __shfl_xor(v, 2);
        v += __shfl_xor(v, 4); v += __shfl_xor(v, 8);
        acc[i] = v;
      }
      if (tl == 0) {
#pragma unroll
        for (int i = 0; i < 8; ++i) fcv[obase + i] = acc[i] + blin[obase + i];
      }
    }
  }
  __syncthreads();   // covers P4 xd writes + P5 fcv

  // ---- P6: fused = out_diff @ Wd^T (+fcv), MFMA; wave w owns o in [w*128, w*128+128) ----
  {
    float4v acc[8];
#pragma unroll
    for (int i = 0; i < 8; ++i) acc[i] = (float4v){0.f, 0.f, 0.f, 0.f};
    const half8v* pk = (const half8v*)PK6;
#pragma unroll 1
    for (int ks = 0; ks < 32; ++ks) {
      half8v a = *(const half8v*)(smem + SM_XD + tl * 2064 + ks * 64 + q * 16);
      half8v bf[8];
#pragma unroll
      for (int t8 = 0; t8 < 8; ++t8)
        bf[t8] = pk[(size_t)((wave * 8 + t8) * 32 + ks) * 64 + lane];
#pragma unroll
      for (int t8 = 0; t8 < 8; ++t8)
        acc[t8] = __builtin_amdgcn_mfma_f32_16x16x32_f16(a, bf[t8], acc[t8], 0, 0, 0);
    }
#pragma unroll
    for (int t8 = 0; t8 < 8; ++t8) {
      int o = (wave * 8 + t8) * 16 + tl;
      float fc = fcv[o];
#pragma unroll
      for (int r = 0; r < 4; ++r) {
        int row = q * 4 + r;
        *(__half*)(smem + SM_FU + row * 1040 + o * 2) = __float2half(acc[t8][r] + fc);
      }
    }
  }
  __syncthreads();

  // ---- P7: h = fused @ Wc^T, MFMA; then max_k + stats (rows = kk) ----
  {
    constexpr int NT = O2 / 64;   // n-tiles per wave
    float4v acc[NT];
#pragma unroll
    for (int i = 0; i < NT; ++i) acc[i] = (float4v){0.f, 0.f, 0.f, 0.f};
    const half8v* pk = (const half8v*)PK7;
#pragma unroll 1
    for (int ks = 0; ks < 16; ++ks) {
      half8v a = *(const half8v*)(smem + SM_FU + tl * 1040 + ks * 64 + q * 16);
      half8v bf[NT];
#pragma unroll
      for (int t = 0; t < NT; ++t)
        bf[t] = pk[(size_t)((wave * NT + t) * 16 + ks) * 64 + lane];
#pragma unroll
      for (int t = 0; t < NT; ++t)
        acc[t] = __builtin_amdgcn_mfma_f32_16x16x32_f16(a, bf[t], acc[t], 0, 0, 0);
    }
    const int slot = blockIdx.x & 63;
#pragma unroll
    for (int t = 0; t < NT; ++t) {
      int o2 = (wave * NT + t) * 16 + tl;
      float mx = -1e30f, s1 = 0.f, s2 = 0.f;
#pragma unroll
      for (int r = 0; r < 4; ++r) {
        int row = q * 4 + r;
        if (row < 10) {
          float v = acc[t][r];
          mx = fmaxf(mx, v);
          s1 += v;
          s2 = fmaf(v, v, s2);
        }
      }
      mx = fmaxf(mx, __shfl_xor(mx, 16)); mx = fmaxf(mx, __shfl_xor(mx, 32));
      s1 += __shfl_xor(s1, 16); s1 += __shfl_xor(s1, 32);
      s2 += __shfl_xor(s2, 16); s2 += __shfl_xor(s2, 32);
      if (q == 0) {
        hmax[((size_t)(b * O2 + o2) << 12) + n] = mx;
        atomicAdd(&S1[(size_t)(slot * 2 + b) * O2 + o2], s1);
        atomicAdd(&S2[(size_t)(slot * 2 + b) * O2 + o2], s2);
      }
    }
  }
}

// ---------------- stats reduce ----------------
__global__ void gcn_stats(const float* __restrict__ S1, const float* __restrict__ S2,
                          float* __restrict__ mu, float* __restrict__ rs,
                          int O2, float invNK) {
  int t = threadIdx.x;
  if (t < 2 * O2) {
    float s1 = 0.f, s2 = 0.f;
    for (int s = 0; s < 64; ++s) {
      s1 += S1[(size_t)s * 2 * O2 + t];
      s2 += S2[(size_t)s * 2 * O2 + t];
    }
    float m = s1 * invNK;
    float var = s2 * invNK - m * m;
    mu[t] = m;
    rs[t] = 1.0f / sqrtf(var + 1e-5f);
  }
}

// ---------------- normalize + lrelu; optional transposed copy ----------------
__global__ void gcn_norm(const float* __restrict__ src, const float* __restrict__ mu,
                         const float* __restrict__ rs, float* __restrict__ fN,
                         float* __restrict__ fT) {
  int idx = blockIdx.x * 256 + threadIdx.x;
  int n = idx & 4095;
  int bo = idx >> 12;
  float v = (src[idx] - mu[bo]) * rs[bo];
  v = v > 0.f ? v : 0.2f * v;
  fN[idx] = v;
  if (fT != nullptr) {
    int o = bo & 255;
    int b = bo >> 8;
    fT[((size_t)((b << 12) + n)) * 256 + o] = v;
  }
}

// ---------------- final conv ----------------
__global__ __launch_bounds__(256, 2) void gcn_final_conv(
    const float* __restrict__ feats, const float* __restrict__ f1N,
    const float* __restrict__ f2N, const float* __restrict__ Wc3,
    float* __restrict__ h3, float* __restrict__ S1, float* __restrict__ S2) {
  __shared__ float ftile[128 * 64];
  int x = blockIdx.x;
  int ob = x & 3, nb = (x >> 2) & 63, b = x >> 8;
  int lane = threadIdx.x & 63, wave = threadIdx.x >> 6;
  int n0 = nb * 64, o0 = ob * 64;
  float acc[16];
#pragma unroll
  for (int i = 0; i < 16; ++i) acc[i] = 0.f;
  for (int ct = 0; ct < 8; ++ct) {
    int cg0 = ct * 128;
    __syncthreads();
    for (int idx = threadIdx.x; idx < 8192; idx += 256) {
      int ccc = idx >> 6, ln = idx & 63;
      int c = cg0 + ccc;
      float v;
      if (c < 256)      v = feats[((size_t)(b * 256 + c) << 12) + n0 + ln];
      else if (c < 512) v = f1N[((size_t)(b * 256 + (c - 256)) << 12) + n0 + ln];
      else              v = f2N[((size_t)(b * 512 + (c - 512)) << 12) + n0 + ln];
      ftile[ccc * 64 + ln] = v;
    }
    __syncthreads();
    for (int c = 0; c < 128; ++c) {
      float fv = ftile[c * 64 + lane];
#pragma unroll
      for (int oi = 0; oi < 16; ++oi) {
        int o = o0 + wave * 16 + oi;
        acc[oi] = fmaf(Wc3[(size_t)o * 1024 + cg0 + c], fv, acc[oi]);
      }
    }
  }
  int slot = nb;
#pragma unroll
  for (int oi = 0; oi < 16; ++oi) {
    int o = o0 + wave * 16 + oi;
    float v = acc[oi];
    h3[((size_t)(b * 256 + o) << 12) + n0 + lane] = v;
    float s1 = v, s2 = v * v;
#pragma unroll
    for (int m = 1; m < 64; m <<= 1) {
      s1 += __shfl_xor(s1, m);
      s2 += __shfl_xor(s2, m);
    }
    if (lane == 0) {
      atomicAdd(&S1[(size_t)(slot * 2 + b) * 256 + o], s1);
      atomicAdd(&S2[(size_t)(slot * 2 + b) * 256 + o], s2);
    }
  }
}

// ---------------- launch ----------------
extern "C" void kernel_launch(void* const* d_in, const int* in_sizes, int n_in,
                              void* d_out, int out_size, void* d_ws, size_t ws_size,
                              hipStream_t stream) {
  (void)in_sizes; (void)n_in; (void)out_size; (void)ws_size;
  const float* coords  = (const float*)d_in[0];
  const float* feats   = (const float*)d_in[1];
  const float* W_lin1  = (const float*)d_in[2];
  const float* b_lin1  = (const float*)d_in[3];
  const float* W_lin2  = (const float*)d_in[4];
  const float* b_lin2  = (const float*)d_in[5];
  const float* W_conv1 = (const float*)d_in[6];
  const float* W_conv2 = (const float*)d_in[7];
  const float* W_conv3 = (const float*)d_in[8];
  char* ws = (char*)d_ws;

  float* F_MM    = (float*)(ws + OFF_MM);
  unsigned long long* KEYS = (unsigned long long*)(ws + OFF_KEYS);
  int* INDS      = (int*)(ws + OFF_INDS);
  _Float16* PK61 = (_Float16*)(ws + OFF_PK6_1);
  _Float16* PK62 = (_Float16*)(ws + OFF_PK6_2);
  __half* WF1    = (__half*)(ws + OFF_WF1);
  __half* WF2    = (__half*)(ws + OFF_WF2);
  _Float16* PK71 = (_Float16*)(ws + OFF_PK7_1);
  _Float16* PK72 = (_Float16*)(ws + OFF_PK7_2);
  float* FEATST  = (float*)(ws + OFF_FEATST);
  float* F1T     = (float*)(ws + OFF_F1T);
  float* F1N     = (float*)(ws + OFF_F1N);
  float* F2N     = (float*)(ws + OFF_F2N);
  float* HMAX1   = (float*)(ws + OFF_HMAX1);
  float* HMAX2   = (float*)(ws + OFF_HMAX2);
  float* H3      = (float*)(ws + OFF_H3);

  (void)hipMemsetAsync(ws + OFF_S1a, 0, STATS_BYTES, stream);

  // weight packing
  gcn_pack6<<<256, 256, 0, stream>>>(W_lin1, PK61);
  gcn_pack6<<<256, 256, 0, stream>>>(W_lin2, PK62);
  gcn_pack7<<<64,  256, 0, stream>>>(W_conv1, PK71);
  gcn_pack7<<<128, 256, 0, stream>>>(W_conv2, PK72);
  gcn_fold<<<512, 256, 0, stream>>>(W_lin1, WF1);
  gcn_fold<<<512, 256, 0, stream>>>(W_lin2, WF2);

  // keys + sort + windows
  gcn_minmax<<<6, 256, 0, stream>>>(coords, F_MM);
  gcn_keys<<<32, 256, 0, stream>>>(coords, F_MM, KEYS);
  gcn_sort<<<8, 512, 0, stream>>>(KEYS, INDS);
  gcn_transpose<<<2048, 256, 0, stream>>>(feats, FEATST);

  // layer 1 (perm1 = [2,0,3,1])
  gcn_window<256><<<8192, 256, 0, stream>>>(
      FEATST, INDS, PK61, WF1, b_lin1, PK71,
      HMAX1, (float*)(ws + OFF_S1a), (float*)(ws + OFF_S2a), 2, 0, 3, 1);
  gcn_stats<<<1, 1024, 0, stream>>>((float*)(ws + OFF_S1a), (float*)(ws + OFF_S2a),
                                    (float*)(ws + OFF_MU1), (float*)(ws + OFF_RS1),
                                    256, 1.0f / 40960.0f);
  gcn_norm<<<8192, 256, 0, stream>>>(HMAX1, (float*)(ws + OFF_MU1), (float*)(ws + OFF_RS1),
                                     F1N, F1T);

  // layer 2 (perm2 = [1,3,0,2])
  gcn_window<512><<<8192, 256, 0, stream>>>(
      F1T, INDS, PK62, WF2, b_lin2, PK72,
      HMAX2, (float*)(ws + OFF_S1b), (float*)(ws + OFF_S2b), 1, 3, 0, 2);
  gcn_stats<<<1, 1024, 0, stream>>>((float*)(ws + OFF_S1b), (float*)(ws + OFF_S2b),
                                    (float*)(ws + OFF_MU2), (float*)(ws + OFF_RS2),
                                    512, 1.0f / 40960.0f);
  gcn_norm<<<16384, 256, 0, stream>>>(HMAX2, (float*)(ws + OFF_MU2), (float*)(ws + OFF_RS2),
                                      F2N, nullptr);

  // final conv + norm
  gcn_final_conv<<<512, 256, 0, stream>>>(feats, F1N, F2N, W_conv3,
                                          H3, (float*)(ws + OFF_S1f), (float*)(ws + OFF_S2f));
  gcn_stats<<<1, 1024, 0, stream>>>((float*)(ws + OFF_S1f), (float*)(ws + OFF_S2f),
                                    (float*)(ws + OFF_MU3), (float*)(ws + OFF_RS3),
                                    256, 1.0f / 4096.0f);
  gcn_norm<<<8192, 256, 0, stream>>>(H3, (float*)(ws + OFF_MU3), (float*)(ws + OFF_RS3),
                                     (float*)d_out, nullptr);
}

// Round 3
// 1264.238 us; speedup vs baseline: 3.8526x; 1.7016x over previous
//
#include <hip/hip_runtime.h>
#include <hip/hip_fp16.h>

// =====================================================================
// GCN pipeline on MI355X, round 3: G=4 window batching + head-chunked
// attention/GEMM pipeline + hoisted center path (hc precompute).
//  - window kernel: 512 thr, 4 windows/block, M=40 (3 MFMA row-tiles)
//  - per-head phases keep LDS at 50.5 KB; P6 accumulates in registers
//  - center contribution folded through conv: hc = F @ (Wc@Wfold)^T + Wc@b
// =====================================================================

typedef _Float16 half8v  __attribute__((ext_vector_type(8)));
typedef float    float4v __attribute__((ext_vector_type(4)));

// ---------------- workspace layout (bytes) ----------------
constexpr size_t OFF_S1a    = 0;
constexpr size_t OFF_S2a    = OFF_S1a + 64ull*2*256*4;
constexpr size_t OFF_S1b    = OFF_S2a + 64ull*2*256*4;
constexpr size_t OFF_S2b    = OFF_S1b + 64ull*2*512*4;
constexpr size_t OFF_S1f    = OFF_S2b + 64ull*2*512*4;
constexpr size_t OFF_S2f    = OFF_S1f + 64ull*2*256*4;
constexpr size_t STATS_BYTES= OFF_S2f + 64ull*2*256*4;      // zeroed each call
constexpr size_t OFF_MU1    = STATS_BYTES;
constexpr size_t OFF_RS1    = OFF_MU1 + 2048;
constexpr size_t OFF_MU2    = OFF_RS1 + 2048;
constexpr size_t OFF_RS2    = OFF_MU2 + 4096;
constexpr size_t OFF_MU3    = OFF_RS2 + 4096;
constexpr size_t OFF_RS3    = OFF_MU3 + 2048;
constexpr size_t OFF_MM     = OFF_RS3 + 2048;               // 12 floats
constexpr size_t OFF_KEYS   = OFF_MM + 256;
constexpr size_t OFF_INDS   = OFF_KEYS + 8ull*4096*8;
constexpr size_t OFF_PK6_1  = OFF_INDS + 8ull*4096*10*4;    // 1 MB
constexpr size_t OFF_PK6_2  = OFF_PK6_1 + 512ull*2048*2;    // 1 MB
constexpr size_t OFF_PK7_1  = OFF_PK6_2 + 512ull*2048*2;    // 256 KB
constexpr size_t OFF_PK7_2  = OFF_PK7_1 + 256ull*512*2;     // 512 KB
constexpr size_t OFF_WFOLD1 = OFF_PK7_2 + 512ull*512*2;     // 512 KB fp32
constexpr size_t OFF_WFOLD2 = OFF_WFOLD1 + 512ull*256*4;
constexpr size_t OFF_WCOMB1 = OFF_WFOLD2 + 512ull*256*4;    // 256 KB
constexpr size_t OFF_WCOMB2 = OFF_WCOMB1 + 256ull*256*4;    // 512 KB
constexpr size_t OFF_PC1    = OFF_WCOMB2 + 512ull*256*4;    // 128 KB
constexpr size_t OFF_PC2    = OFF_PC1 + 256ull*256*2;       // 256 KB
constexpr size_t OFF_BC1    = OFF_PC2 + 512ull*256*2;
constexpr size_t OFF_BC2    = OFF_BC1 + 1024;
constexpr size_t OFF_FEATST = OFF_BC2 + 2048;               // (B,N,256) fp32, 8 MB
constexpr size_t OFF_F1T    = OFF_FEATST + 2ull*4096*256*4; // (B,N,256)
constexpr size_t OFF_F2N    = OFF_F1T   + 2ull*4096*256*4;  // (B,512,N) 16 MB
constexpr size_t OFF_HMAX1  = OFF_F2N   + 2ull*4096*512*4;  // (B,256,N)
constexpr size_t OFF_HMAX2  = OFF_HMAX1 + 2ull*4096*256*4;  // (B,512,N)
constexpr size_t OFF_HC2    = OFF_HMAX2 + 2ull*4096*512*4;  // 8192x512 fp32, 16 MB
constexpr size_t WS_NEED    = OFF_HC2   + 8192ull*512*4;    // ~90 MB
// lifetime-disjoint aliases:
constexpr size_t OFF_F1N    = OFF_FEATST;  // featsT dead after window1/hc1
constexpr size_t OFF_H3     = OFF_HMAX1;   // hmax1 dead after norm1
constexpr size_t OFF_HC1    = OFF_F2N;     // F2N untouched until norm2; hc1 dead after window1

// ---------------- helpers ----------------
__device__ __forceinline__ int gcn_quant1(float c, float cmin, float scale) {
  float q = floorf(__fmul_rn(__fsub_rn(c, cmin), scale));
  q = fminf(fmaxf(q, 0.0f), 1023.0f);
  return (int)q;
}

__device__ __forceinline__ unsigned int gcn_morton3(int x, int y, int z) {
  unsigned int key = 0u;
#pragma unroll
  for (int b = 0; b < 10; ++b) {
    key |= ((unsigned)((x >> b) & 1)) << (3 * b + 2);
    key |= ((unsigned)((y >> b) & 1)) << (3 * b + 1);
    key |= ((unsigned)((z >> b) & 1)) << (3 * b + 0);
  }
  return key;
}

__device__ __forceinline__ unsigned int gcn_hilbert3(int x, int y, int z) {
  int X0 = x, X1 = y, X2 = z;
  for (int Q = 512; Q > 1; Q >>= 1) {
    int P = Q - 1;
    if (X0 & Q) X0 ^= P;
    {
      int t = (X0 ^ X1) & P;
      if (X1 & Q) { X0 ^= P; } else { X0 ^= t; X1 ^= t; }
    }
    {
      int t = (X0 ^ X2) & P;
      if (X2 & Q) { X0 ^= P; } else { X0 ^= t; X2 ^= t; }
    }
  }
  X1 ^= X0;
  X2 ^= X1;
  int t = 0;
  for (int Q = 512; Q > 1; Q >>= 1)
    if (X2 & Q) t ^= (Q - 1);
  X0 ^= t; X1 ^= t; X2 ^= t;
  unsigned int key = 0u;
#pragma unroll
  for (int b = 9; b >= 0; --b) {
    key = (key << 1) | (unsigned)((X0 >> b) & 1);
    key = (key << 1) | (unsigned)((X1 >> b) & 1);
    key = (key << 1) | (unsigned)((X2 >> b) & 1);
  }
  return key;
}

// ---------------- weight prep ----------------
// WfoldF[o][c] = sum_j W[o][4c+j] (fp32)
__global__ void gcn_foldF(const float* __restrict__ W, float* __restrict__ Wf) {
  int i = blockIdx.x * 256 + threadIdx.x;   // 512*256
  int o = i >> 8, c = i & 255;
  float4 w = ((const float4*)W)[(size_t)o * 512 + c];
  Wf[i] = w.x + w.y + w.z + w.w;
}

// Wcomb[o2][c] = sum_o Wc[o2][o] * WfoldF[o][c]; bc[o2] = Wc[o2,:].b
__global__ void gcn_wcomb(const float* __restrict__ Wc, const float* __restrict__ blin,
                          const float* __restrict__ WfoldF, float* __restrict__ Wcomb,
                          float* __restrict__ bc) {
  __shared__ float wrow[512];
  int o2 = blockIdx.x, tid = threadIdx.x;
  wrow[tid] = Wc[(size_t)o2 * 512 + tid];
  wrow[tid + 256] = Wc[(size_t)o2 * 512 + tid + 256];
  __syncthreads();
  float acc = 0.f;
  for (int o = 0; o < 512; ++o)
    acc = fmaf(wrow[o], WfoldF[(size_t)o * 256 + tid], acc);
  Wcomb[(size_t)o2 * 256 + tid] = acc;
  if (tid == 0) {
    float s = 0.f;
    for (int o = 0; o < 512; ++o) s += wrow[o] * blin[o];
    bc[o2] = s;
  }
}

// fragment pack of Wcomb for hc GEMM: B[k=c][n=o2]
__global__ void gcn_packC(const float* __restrict__ Wcomb, _Float16* __restrict__ P) {
  int i = blockIdx.x * 256 + threadIdx.x;   // (O2/16)*8*64 threads
  int lane = i & 63, ks = (i >> 6) & 7, nt = i >> 9;
  int tl = lane & 15, q = lane >> 4;
  int n = nt * 16 + tl;
  _Float16 tmp[8];
#pragma unroll
  for (int j = 0; j < 8; ++j)
    tmp[j] = (_Float16)Wcomb[(size_t)n * 256 + ks * 32 + q * 8 + j];
  *(half8v*)(P + (size_t)i * 8) = *(half8v*)tmp;
}

// P6 B-frag pack: frag f=(nt*32+ks)*64+lane; k_global -> orig col 1024+k
__global__ void gcn_pack6(const float* __restrict__ W, _Float16* __restrict__ P) {
  int i = blockIdx.x * 256 + threadIdx.x;   // 65536
  int lane = i & 63, ks = (i >> 6) & 31, nt = i >> 11;
  int tl = lane & 15, q = lane >> 4;
  int o = nt * 16 + tl;
  _Float16 tmp[8];
#pragma unroll
  for (int j = 0; j < 8; ++j) {
    int k = ks * 32 + q * 8 + j;
    tmp[j] = (_Float16)W[(size_t)o * 2048 + 1024 + k];
  }
  *(half8v*)(P + (size_t)i * 8) = *(half8v*)tmp;
}

// P7 B-frag pack: frag f=(nt*16+ks)*64+lane, B[k=c2][n=o2]=Wc[o2][c2]
__global__ void gcn_pack7(const float* __restrict__ W, _Float16* __restrict__ P) {
  int i = blockIdx.x * 256 + threadIdx.x;   // O2*64
  int lane = i & 63, ks = (i >> 6) & 15, nt = i >> 10;
  int tl = lane & 15, q = lane >> 4;
  int o2 = nt * 16 + tl;
  int c2 = ks * 32 + q * 8;
  _Float16 tmp[8];
#pragma unroll
  for (int j = 0; j < 8; ++j)
    tmp[j] = (_Float16)W[(size_t)o2 * 512 + c2 + j];
  *(half8v*)(P + (size_t)i * 8) = *(half8v*)tmp;
}

// ---------------- hc precompute: out[row][o2] = src[row,:].Wcomb[o2,:] + bc ----------------
template <int O2>
__global__ __launch_bounds__(256) void gcn_hc(const float* __restrict__ src,
                                              const _Float16* __restrict__ PC,
                                              const float* __restrict__ bc,
                                              float* __restrict__ out) {
  constexpr int NB = O2 / 64;
  __shared__ __align__(16) _Float16 As[64 * 264];
  int nb = blockIdx.x % NB, mb = blockIdx.x / NB;
  int tid = threadIdx.x;
#pragma unroll 4
  for (int k = 0; k < 64; ++k)
    As[k * 264 + tid] = (_Float16)src[((size_t)(mb * 64 + k)) * 256 + tid];
  __syncthreads();
  int lane = tid & 63, w = tid >> 6, tl = lane & 15, q = lane >> 4;
  float4v acc[4];
#pragma unroll
  for (int t = 0; t < 4; ++t) acc[t] = (float4v){0.f, 0.f, 0.f, 0.f};
  const half8v* pc = (const half8v*)PC;
#pragma unroll
  for (int ks = 0; ks < 8; ++ks) {
    half8v a = *(const half8v*)((const char*)As + (w * 16 + tl) * 528 + ks * 64 + q * 16);
#pragma unroll
    for (int t = 0; t < 4; ++t) {
      half8v bf = pc[(size_t)(((nb * 4 + t) * 8 + ks)) * 64 + lane];
      acc[t] = __builtin_amdgcn_mfma_f32_16x16x32_f16(a, bf, acc[t], 0, 0, 0);
    }
  }
#pragma unroll
  for (int t = 0; t < 4; ++t) {
    int o = (nb * 4 + t) * 16 + tl;
    float bb = bc[o];
#pragma unroll
    for (int r = 0; r < 4; ++r) {
      int row = mb * 64 + w * 16 + q * 4 + r;
      out[(size_t)row * O2 + o] = acc[t][r] + bb;
    }
  }
}

// ---------------- quantize prep ----------------
__global__ void gcn_minmax(const float* __restrict__ coords, float* __restrict__ mm) {
  __shared__ float slo[256], shi[256];
  int d = blockIdx.x, tid = threadIdx.x;
  float lo = 1e30f, hi = -1e30f;
  for (int i = tid; i < 4096; i += 256) {
    float v = coords[(size_t)d * 4096 + i];
    lo = fminf(lo, v);
    hi = fmaxf(hi, v);
  }
  slo[tid] = lo; shi[tid] = hi;
  __syncthreads();
  for (int s = 128; s > 0; s >>= 1) {
    if (tid < s) {
      slo[tid] = fminf(slo[tid], slo[tid + s]);
      shi[tid] = fmaxf(shi[tid], shi[tid + s]);
    }
    __syncthreads();
  }
  if (tid == 0) {
    mm[d] = slo[0];
    mm[6 + d] = 1023.0f / ((shi[0] - slo[0]) + 1e-6f);
  }
}

__global__ void gcn_keys(const float* __restrict__ coords, const float* __restrict__ mm,
                         unsigned long long* __restrict__ keys) {
  int idx = blockIdx.x * 256 + threadIdx.x;
  int b = idx >> 12, n = idx & 4095;
  const float* cb = coords + (size_t)b * 3 * 4096;
  int q0 = gcn_quant1(cb[n],        mm[b * 3 + 0], mm[6 + b * 3 + 0]);
  int q1 = gcn_quant1(cb[4096 + n], mm[b * 3 + 1], mm[6 + b * 3 + 1]);
  int q2 = gcn_quant1(cb[8192 + n], mm[b * 3 + 2], mm[6 + b * 3 + 2]);
  unsigned long long nn = (unsigned long long)(unsigned)n;
  size_t base = ((size_t)b * 4) * 4096 + n;
  keys[base]         = ((unsigned long long)gcn_morton3(q0, q1, q2) << 12) | nn;
  keys[base + 4096]  = ((unsigned long long)gcn_morton3(q1, q0, q2) << 12) | nn;
  keys[base + 8192]  = ((unsigned long long)gcn_hilbert3(q0, q1, q2) << 12) | nn;
  keys[base + 12288] = ((unsigned long long)gcn_hilbert3(q1, q0, q2) << 12) | nn;
}

// ---------------- bitonic sort (stable argsort replica) + windows ----------------
__global__ __launch_bounds__(512) void gcn_sort(const unsigned long long* __restrict__ keys,
                                                int* __restrict__ inds) {
  __shared__ unsigned long long a[4096];
  int g = blockIdx.x, tid = threadIdx.x;
  for (int i = tid; i < 4096; i += 512) a[i] = keys[(size_t)g * 4096 + i];
  __syncthreads();
  for (int k = 2; k <= 4096; k <<= 1) {
    for (int j = k >> 1; j > 0; j >>= 1) {
      for (int t = tid; t < 2048; t += 512) {
        int i = 2 * t - (t & (j - 1));
        int p = i + j;
        bool up = (i & k) == 0;
        unsigned long long x = a[i], y = a[p];
        if ((x > y) == up) { a[i] = y; a[p] = x; }
      }
      __syncthreads();
    }
  }
  for (int i = tid; i < 4096; i += 512) {
    int start = i - 5; if (start < 0) start = 0;
    int endm1 = i + 5; if (endm1 > 4095) endm1 = 4095;
#pragma unroll
    for (int kk = 0; kk < 10; ++kk) {
      int pos = start + kk; if (pos > endm1) pos = endm1;
      inds[((size_t)g * 4096 + i) * 10 + kk] = (int)(a[pos] & 0xFFFULL);
    }
  }
}

// ---------------- transpose (B,C,N) -> (B,N,C) ----------------
__global__ void gcn_transpose(const float* __restrict__ feats, float* __restrict__ fT) {
  __shared__ float t[32][33];
  int blk = blockIdx.x;
  int cb = blk & 7, nb = (blk >> 3) & 127, b = blk >> 10;
  int tx = threadIdx.x & 31, ty = threadIdx.x >> 5;
#pragma unroll
  for (int i = 0; i < 4; ++i) {
    int c = cb * 32 + ty + i * 8;
    t[ty + i * 8][tx] = feats[((size_t)(b * 256 + c) << 12) + nb * 32 + tx];
  }
  __syncthreads();
#pragma unroll
  for (int i = 0; i < 4; ++i) {
    int n = nb * 32 + ty + i * 8;
    fT[((size_t)((b << 12) + n)) * 256 + cb * 32 + tx] = t[tx][ty + i * 8];
  }
}

// ---------------- fused 4-window MFMA kernel ----------------
// LDS: XD (head slab) 48 rows x 264 halves = 25,344 B at 0
//      SC 1600 f at 25,344 (6,400 B)
//      FU 48 rows x 520 halves = 49,920 B at 0 (aliases XD+SC; disjoint in time)
//      IDX 160 ints at 49,920
constexpr int XD_ROWB = 528;
constexpr int FU_ROWB = 1040;
constexpr int SM_SC   = 25344;
constexpr int SM_IDX  = 49920;
constexpr int SM_TOT  = 50560;

template <int O2>
__global__ __launch_bounds__(512, 4) void gcn_window(
    const float* __restrict__ fT, const int* __restrict__ inds,
    const _Float16* __restrict__ PK6, const _Float16* __restrict__ PK7,
    const float* __restrict__ hc,
    float* __restrict__ hmax, float* __restrict__ S1, float* __restrict__ S2,
    int p0, int p1, int p2, int p3) {
  __shared__ __align__(16) char smem[SM_TOT];
  float* sc  = (float*)(smem + SM_SC);
  int*   idx = (int*)(smem + SM_IDX);

  const int tid = threadIdx.x;
  const int lane = tid & 63, w = tid >> 6;
  const int tl = lane & 15, q = lane >> 4;
  const int b = blockIdx.x >> 10;
  const int n0 = (blockIdx.x & 1023) * 4;
  const float* fTb = fT + ((size_t)(b << 12)) * 256;

  // stage window indices: idx[(g*4+m)*10+kk]
  if (tid < 160) {
    int g = tid / 40, rem = tid % 40, m = rem / 10, kk = rem % 10;
    int meth = (m == 0) ? p0 : (m == 1) ? p1 : (m == 2) ? p2 : p3;
    idx[tid] = inds[((size_t)((b * 4 + meth) << 12) + n0 + g) * 10 + kk];
  }
  __syncthreads();

  float4v acc6[3][4];
#pragma unroll
  for (int mt = 0; mt < 3; ++mt)
#pragma unroll
    for (int t = 0; t < 4; ++t) acc6[mt][t] = (float4v){0.f, 0.f, 0.f, 0.f};

  const half8v* pk6 = (const half8v*)PK6;

#pragma unroll 1
  for (int h = 0; h < 4; ++h) {
    // ---- P1: gather head slab, diff, fp16; col d' = 4*lane + m ----
#pragma unroll
    for (int s = 0; s < 2; ++s) {
      int tk = w * 2 + s;
      int g = tk >> 2, m = tk & 3;
      float cv = fTb[(size_t)(n0 + g) * 256 + h * 64 + lane];
      const int* ir = idx + (g * 4 + m) * 10;
#pragma unroll
      for (int kk = 0; kk < 10; ++kk) {
        float v = fTb[(size_t)ir[kk] * 256 + h * 64 + lane];
        *(__half*)(smem + (g * 10 + kk) * XD_ROWB + lane * 8 + m * 2) =
            __float2half(v - cv);
      }
    }
    __syncthreads();

    // ---- P2: scores for head 4+h via MFMA (waves 0..3 = windows) ----
    if (w < 4) {
      float4v accs = {0.f, 0.f, 0.f, 0.f};
#pragma unroll
      for (int ks = 0; ks < 8; ++ks) {
        half8v a = *(const half8v*)(smem + (w * 10 + tl) * XD_ROWB + ks * 64 + q * 16);
        accs = __builtin_amdgcn_mfma_f32_16x16x32_f16(a, a, accs, 0, 0, 0);
      }
#pragma unroll
      for (int r = 0; r < 4; ++r) {
        int row = q * 4 + r;
        if (row < 10 && tl < 10)
          sc[w * 100 + row * 10 + tl] = accs[r] * 0.0625f;
      }
    }
    __syncthreads();

    // ---- P3: softmax over j ----
    if (tid < 40) {
      int g = tid / 10, row = tid % 10;
      float s[10];
      float m = -1e30f;
#pragma unroll
      for (int j = 0; j < 10; ++j) { s[j] = sc[g * 100 + row * 10 + j]; m = fmaxf(m, s[j]); }
      float sum = 0.f;
#pragma unroll
      for (int j = 0; j < 10; ++j) { s[j] = expf(s[j] - m); sum += s[j]; }
      float inv = 1.0f / sum;
#pragma unroll
      for (int j = 0; j < 10; ++j) sc[g * 100 + row * 10 + j] = s[j] * inv;
    }
    __syncthreads();

    // ---- P4: out = attn @ x_diff, column-owned in place ----
    {
      int g = tid >> 7, cp = tid & 127;
      float2 xv[10];
#pragma unroll
      for (int j = 0; j < 10; ++j)
        xv[j] = __half22float2(*(const __half2*)(smem + (g * 10 + j) * XD_ROWB + cp * 4));
#pragma unroll
      for (int kk = 0; kk < 10; ++kk) {
        const float* arow = sc + g * 100 + kk * 10;
        float ax = 0.f, ay = 0.f;
#pragma unroll
        for (int j = 0; j < 10; ++j) {
          float wj = arow[j];
          ax = fmaf(wj, xv[j].x, ax);
          ay = fmaf(wj, xv[j].y, ay);
        }
        *(__half2*)(smem + (g * 10 + kk) * XD_ROWB + cp * 4) = __floats2half2_rn(ax, ay);
      }
    }
    __syncthreads();

    // ---- P6 partial: acc6 += out_slab @ Wd_slab^T ----
#pragma unroll
    for (int ks = 0; ks < 8; ++ks) {
      int ksg = h * 8 + ks;
      half8v a0 = *(const half8v*)(smem + (0  + tl) * XD_ROWB + ks * 64 + q * 16);
      half8v a1 = *(const half8v*)(smem + (16 + tl) * XD_ROWB + ks * 64 + q * 16);
      half8v a2 = *(const half8v*)(smem + (32 + tl) * XD_ROWB + ks * 64 + q * 16);
#pragma unroll
      for (int t = 0; t < 4; ++t) {
        half8v bf = pk6[(size_t)(((w * 4 + t) * 32 + ksg)) * 64 + lane];
        acc6[0][t] = __builtin_amdgcn_mfma_f32_16x16x32_f16(a0, bf, acc6[0][t], 0, 0, 0);
        acc6[1][t] = __builtin_amdgcn_mfma_f32_16x16x32_f16(a1, bf, acc6[1][t], 0, 0, 0);
        acc6[2][t] = __builtin_amdgcn_mfma_f32_16x16x32_f16(a2, bf, acc6[2][t], 0, 0, 0);
      }
    }
    __syncthreads();   // XD slab reused next phase; also orders last phase vs FU
  }

  // ---- write FU (aliases XD region; all P6 reads done) ----
#pragma unroll
  for (int mt = 0; mt < 3; ++mt)
#pragma unroll
    for (int t = 0; t < 4; ++t) {
      int o = (w * 4 + t) * 16 + tl;
#pragma unroll
      for (int r = 0; r < 4; ++r) {
        int row = 16 * mt + q * 4 + r;
        *(__half*)(smem + row * FU_ROWB + o * 2) = __float2half(acc6[mt][t][r]);
      }
    }
  __syncthreads();

  // ---- P7: h = fused @ Wc^T + hc, then max_k + stats ----
  {
    constexpr int NT = O2 / 128;
    float4v acc7[3][NT];
#pragma unroll
    for (int mt = 0; mt < 3; ++mt)
#pragma unroll
      for (int t = 0; t < NT; ++t) acc7[mt][t] = (float4v){0.f, 0.f, 0.f, 0.f};
    const half8v* pk7 = (const half8v*)PK7;
#pragma unroll 1
    for (int ks = 0; ks < 16; ++ks) {
      half8v a0 = *(const half8v*)(smem + (0  + tl) * FU_ROWB + ks * 64 + q * 16);
      half8v a1 = *(const half8v*)(smem + (16 + tl) * FU_ROWB + ks * 64 + q * 16);
      half8v a2 = *(const half8v*)(smem + (32 + tl) * FU_ROWB + ks * 64 + q * 16);
#pragma unroll
      for (int t = 0; t < NT; ++t) {
        half8v bf = pk7[(size_t)(((w * NT + t) * 16 + ks)) * 64 + lane];
        acc7[0][t] = __builtin_amdgcn_mfma_f32_16x16x32_f16(a0, bf, acc7[0][t], 0, 0, 0);
        acc7[1][t] = __builtin_amdgcn_mfma_f32_16x16x32_f16(a1, bf, acc7[1][t], 0, 0, 0);
        acc7[2][t] = __builtin_amdgcn_mfma_f32_16x16x32_f16(a2, bf, acc7[2][t], 0, 0, 0);
      }
    }
    const int slot = blockIdx.x & 63;
#pragma unroll
    for (int t = 0; t < NT; ++t) {
      int o2 = (w * NT + t) * 16 + tl;
      float hcv[4], mx[4], s1[4], s2[4];
#pragma unroll
      for (int g = 0; g < 4; ++g) {
        hcv[g] = hc[((size_t)((b << 12) + n0 + g)) * O2 + o2];
        mx[g] = -1e30f; s1[g] = 0.f; s2[g] = 0.f;
      }
#pragma unroll
      for (int mt = 0; mt < 3; ++mt)
#pragma unroll
        for (int r = 0; r < 4; ++r) {
          int gr = 16 * mt + 4 * q + r;
#pragma unroll
          for (int g = 0; g < 4; ++g) {
            if (gr >= 10 * g && gr < 10 * g + 10) {
              float v = acc7[mt][t][r] + hcv[g];
              mx[g] = fmaxf(mx[g], v);
              s1[g] += v;
              s2[g] = fmaf(v, v, s2[g]);
            }
          }
        }
#pragma unroll
      for (int g = 0; g < 4; ++g) {
        mx[g] = fmaxf(mx[g], __shfl_xor(mx[g], 16));
        mx[g] = fmaxf(mx[g], __shfl_xor(mx[g], 32));
      }
      float s1t = (s1[0] + s1[1]) + (s1[2] + s1[3]);
      float s2t = (s2[0] + s2[1]) + (s2[2] + s2[3]);
      s1t += __shfl_xor(s1t, 16); s1t += __shfl_xor(s1t, 32);
      s2t += __shfl_xor(s2t, 16); s2t += __shfl_xor(s2t, 32);
      if (q == 0) {
        float4 mv = make_float4(mx[0], mx[1], mx[2], mx[3]);
        *(float4*)(hmax + (((size_t)(b * O2 + o2)) << 12) + n0) = mv;
        atomicAdd(&S1[(size_t)(slot * 2 + b) * O2 + o2], s1t);
        atomicAdd(&S2[(size_t)(slot * 2 + b) * O2 + o2], s2t);
      }
    }
  }
}

// ---------------- stats reduce ----------------
__global__ void gcn_stats(const float* __restrict__ S1, const float* __restrict__ S2,
                          float* __restrict__ mu, float* __restrict__ rs,
                          int O2, float invNK) {
  int t = threadIdx.x;
  if (t < 2 * O2) {
    float s1 = 0.f, s2 = 0.f;
    for (int s = 0; s < 64; ++s) {
      s1 += S1[(size_t)s * 2 * O2 + t];
      s2 += S2[(size_t)s * 2 * O2 + t];
    }
    float m = s1 * invNK;
    float var = s2 * invNK - m * m;
    mu[t] = m;
    rs[t] = 1.0f / sqrtf(var + 1e-5f);
  }
}

// ---------------- normalize + lrelu; optional transposed copy ----------------
__global__ void gcn_norm(const float* __restrict__ src, const float* __restrict__ mu,
                         const float* __restrict__ rs, float* __restrict__ fN,
                         float* __restrict__ fT) {
  int idx = blockIdx.x * 256 + threadIdx.x;
  int n = idx & 4095;
  int bo = idx >> 12;
  float v = (src[idx] - mu[bo]) * rs[bo];
  v = v > 0.f ? v : 0.2f * v;
  fN[idx] = v;
  if (fT != nullptr) {
    int o = bo & 255;
    int b = bo >> 8;
    fT[((size_t)((b << 12) + n)) * 256 + o] = v;
  }
}

// ---------------- final conv ----------------
__global__ __launch_bounds__(256, 2) void gcn_final_conv(
    const float* __restrict__ feats, const float* __restrict__ f1N,
    const float* __restrict__ f2N, const float* __restrict__ Wc3,
    float* __restrict__ h3, float* __restrict__ S1, float* __restrict__ S2) {
  __shared__ float ftile[128 * 64];
  int x = blockIdx.x;
  int ob = x & 3, nb = (x >> 2) & 63, b = x >> 8;
  int lane = threadIdx.x & 63, wave = threadIdx.x >> 6;
  int n0 = nb * 64, o0 = ob * 64;
  float acc[16];
#pragma unroll
  for (int i = 0; i < 16; ++i) acc[i] = 0.f;
  for (int ct = 0; ct < 8; ++ct) {
    int cg0 = ct * 128;
    __syncthreads();
    for (int idx = threadIdx.x; idx < 8192; idx += 256) {
      int ccc = idx >> 6, ln = idx & 63;
      int c = cg0 + ccc;
      float v;
      if (c < 256)      v = feats[((size_t)(b * 256 + c) << 12) + n0 + ln];
      else if (c < 512) v = f1N[((size_t)(b * 256 + (c - 256)) << 12) + n0 + ln];
      else              v = f2N[((size_t)(b * 512 + (c - 512)) << 12) + n0 + ln];
      ftile[ccc * 64 + ln] = v;
    }
    __syncthreads();
    for (int c = 0; c < 128; ++c) {
      float fv = ftile[c * 64 + lane];
#pragma unroll
      for (int oi = 0; oi < 16; ++oi) {
        int o = o0 + wave * 16 + oi;
        acc[oi] = fmaf(Wc3[(size_t)o * 1024 + cg0 + c], fv, acc[oi]);
      }
    }
  }
  int slot = nb;
#pragma unroll
  for (int oi = 0; oi < 16; ++oi) {
    int o = o0 + wave * 16 + oi;
    float v = acc[oi];
    h3[((size_t)(b * 256 + o) << 12) + n0 + lane] = v;
    float s1 = v, s2 = v * v;
#pragma unroll
    for (int m = 1; m < 64; m <<= 1) {
      s1 += __shfl_xor(s1, m);
      s2 += __shfl_xor(s2, m);
    }
    if (lane == 0) {
      atomicAdd(&S1[(size_t)(slot * 2 + b) * 256 + o], s1);
      atomicAdd(&S2[(size_t)(slot * 2 + b) * 256 + o], s2);
    }
  }
}

// ---------------- launch ----------------
extern "C" void kernel_launch(void* const* d_in, const int* in_sizes, int n_in,
                              void* d_out, int out_size, void* d_ws, size_t ws_size,
                              hipStream_t stream) {
  (void)in_sizes; (void)n_in; (void)out_size; (void)ws_size;
  const float* coords  = (const float*)d_in[0];
  const float* feats   = (const float*)d_in[1];
  const float* W_lin1  = (const float*)d_in[2];
  const float* b_lin1  = (const float*)d_in[3];
  const float* W_lin2  = (const float*)d_in[4];
  const float* b_lin2  = (const float*)d_in[5];
  const float* W_conv1 = (const float*)d_in[6];
  const float* W_conv2 = (const float*)d_in[7];
  const float* W_conv3 = (const float*)d_in[8];
  char* ws = (char*)d_ws;

  float* F_MM    = (float*)(ws + OFF_MM);
  unsigned long long* KEYS = (unsigned long long*)(ws + OFF_KEYS);
  int* INDS      = (int*)(ws + OFF_INDS);
  _Float16* PK61 = (_Float16*)(ws + OFF_PK6_1);
  _Float16* PK62 = (_Float16*)(ws + OFF_PK6_2);
  _Float16* PK71 = (_Float16*)(ws + OFF_PK7_1);
  _Float16* PK72 = (_Float16*)(ws + OFF_PK7_2);
  float* WFOLD1  = (float*)(ws + OFF_WFOLD1);
  float* WFOLD2  = (float*)(ws + OFF_WFOLD2);
  float* WCOMB1  = (float*)(ws + OFF_WCOMB1);
  float* WCOMB2  = (float*)(ws + OFF_WCOMB2);
  _Float16* PC1  = (_Float16*)(ws + OFF_PC1);
  _Float16* PC2  = (_Float16*)(ws + OFF_PC2);
  float* BC1     = (float*)(ws + OFF_BC1);
  float* BC2     = (float*)(ws + OFF_BC2);
  float* FEATST  = (float*)(ws + OFF_FEATST);
  float* F1T     = (float*)(ws + OFF_F1T);
  float* F1N     = (float*)(ws + OFF_F1N);
  float* F2N     = (float*)(ws + OFF_F2N);
  float* HMAX1   = (float*)(ws + OFF_HMAX1);
  float* HMAX2   = (float*)(ws + OFF_HMAX2);
  float* HC1     = (float*)(ws + OFF_HC1);
  float* HC2     = (float*)(ws + OFF_HC2);
  float* H3      = (float*)(ws + OFF_H3);

  (void)hipMemsetAsync(ws + OFF_S1a, 0, STATS_BYTES, stream);

  // weight prep
  gcn_foldF<<<512, 256, 0, stream>>>(W_lin1, WFOLD1);
  gcn_foldF<<<512, 256, 0, stream>>>(W_lin2, WFOLD2);
  gcn_wcomb<<<256, 256, 0, stream>>>(W_conv1, b_lin1, WFOLD1, WCOMB1, BC1);
  gcn_wcomb<<<512, 256, 0, stream>>>(W_conv2, b_lin2, WFOLD2, WCOMB2, BC2);
  gcn_packC<<<32, 256, 0, stream>>>(WCOMB1, PC1);
  gcn_packC<<<64, 256, 0, stream>>>(WCOMB2, PC2);
  gcn_pack6<<<256, 256, 0, stream>>>(W_lin1, PK61);
  gcn_pack6<<<256, 256, 0, stream>>>(W_lin2, PK62);
  gcn_pack7<<<64,  256, 0, stream>>>(W_conv1, PK71);
  gcn_pack7<<<128, 256, 0, stream>>>(W_conv2, PK72);

  // keys + sort + transpose
  gcn_minmax<<<6, 256, 0, stream>>>(coords, F_MM);
  gcn_keys<<<32, 256, 0, stream>>>(coords, F_MM, KEYS);
  gcn_sort<<<8, 512, 0, stream>>>(KEYS, INDS);
  gcn_transpose<<<2048, 256, 0, stream>>>(feats, FEATST);

  // layer 1 (perm1 = [2,0,3,1])
  gcn_hc<256><<<512, 256, 0, stream>>>(FEATST, PC1, BC1, HC1);
  gcn_window<256><<<2048, 512, 0, stream>>>(
      FEATST, INDS, PK61, PK71, HC1,
      HMAX1, (float*)(ws + OFF_S1a), (float*)(ws + OFF_S2a), 2, 0, 3, 1);
  gcn_stats<<<1, 1024, 0, stream>>>((float*)(ws + OFF_S1a), (float*)(ws + OFF_S2a),
                                    (float*)(ws + OFF_MU1), (float*)(ws + OFF_RS1),
                                    256, 1.0f / 40960.0f);
  gcn_norm<<<8192, 256, 0, stream>>>(HMAX1, (float*)(ws + OFF_MU1), (float*)(ws + OFF_RS1),
                                     F1N, F1T);

  // layer 2 (perm2 = [1,3,0,2])
  gcn_hc<512><<<1024, 256, 0, stream>>>(F1T, PC2, BC2, HC2);
  gcn_window<512><<<2048, 512, 0, stream>>>(
      F1T, INDS, PK62, PK72, HC2,
      HMAX2, (float*)(ws + OFF_S1b), (float*)(ws + OFF_S2b), 1, 3, 0, 2);
  gcn_stats<<<1, 1024, 0, stream>>>((float*)(ws + OFF_S1b), (float*)(ws + OFF_S2b),
                                    (float*)(ws + OFF_MU2), (float*)(ws + OFF_RS2),
                                    512, 1.0f / 40960.0f);
  gcn_norm<<<16384, 256, 0, stream>>>(HMAX2, (float*)(ws + OFF_MU2), (float*)(ws + OFF_RS2),
                                      F2N, nullptr);

  // final conv + norm
  gcn_final_conv<<<512, 256, 0, stream>>>(feats, F1N, F2N, W_conv3,
                                          H3, (float*)(ws + OFF_S1f), (float*)(ws + OFF_S2f));
  gcn_stats<<<1, 1024, 0, stream>>>((float*)(ws + OFF_S1f), (float*)(ws + OFF_S2f),
                                    (float*)(ws + OFF_MU3), (float*)(ws + OFF_RS3),
                                    256, 1.0f / 4096.0f);
  gcn_norm<<<8192, 256, 0, stream>>>(H3, (float*)(ws + OFF_MU3), (float*)(ws + OFF_RS3),
                                     (float*)d_out, nullptr);
}